// Round 2
// baseline (446.168 us; speedup 1.0000x reference)
//
#include <hip/hip_runtime.h>

#define EPS 1e-5f
#define WPB 4  // waves (rays) per 256-thread block

// DPP move with old=0: masked-out rows / OOB lanes return 0 (identity for sum
// and for max over non-negative values).
template<int CTRL, int RM>
__device__ __forceinline__ float dppf(float v) {
    return __int_as_float(__builtin_amdgcn_update_dpp(
        0, __float_as_int(v), CTRL, RM, 0xf, true));
}
template<int CTRL, int RM>
__device__ __forceinline__ int dppi(int v) {
    return __builtin_amdgcn_update_dpp(0, v, CTRL, RM, 0xf, true);
}

__device__ __forceinline__ float readlane_f(float v, int l) {
    return __int_as_float(__builtin_amdgcn_readlane(__float_as_int(v), l));
}
__device__ __forceinline__ float bperm_f(int byteaddr, float v) {
    return __int_as_float(__builtin_amdgcn_ds_bpermute(byteaddr, __float_as_int(v)));
}

// Inclusive 64-lane sum-scan: 4 row_shr steps + row_bcast15/31 cross-row finish.
__device__ __forceinline__ float wave_scan_sum(float x) {
    x += dppf<0x111, 0xf>(x);   // row_shr:1
    x += dppf<0x112, 0xf>(x);   // row_shr:2
    x += dppf<0x114, 0xf>(x);   // row_shr:4
    x += dppf<0x118, 0xf>(x);   // row_shr:8  -> inclusive within 16-lane row
    x += dppf<0x142, 0xa>(x);   // row_bcast15: rows 1 & 3 += prev-row total
    x += dppf<0x143, 0xc>(x);   // row_bcast31: rows 2 & 3 += lanes0-31 total
    return x;
}

// Inclusive 64-lane max-scan (values >= 0)
__device__ __forceinline__ int wave_scan_max(int x) {
    x = max(x, dppi<0x111, 0xf>(x));
    x = max(x, dppi<0x112, 0xf>(x));
    x = max(x, dppi<0x114, 0xf>(x));
    x = max(x, dppi<0x118, 0xf>(x));
    x = max(x, dppi<0x142, 0xa>(x));
    x = max(x, dppi<0x143, 0xc>(x));
    return x;
}

// One 64-lane wave per ray; lane i holds z[i], w[i]. Pure register-crossbar
// implementation: NO shared memory, NO atomics, NO waitcnt fences.
//
// Scatter-max trick: ds_permute_b32 writes into a zero-initialized 64-slot
// temp with lanes processed in order (highest lane wins on collisions) and
// untargeted lanes receiving 0. Since our pushed value (lane+1) is increasing
// in lane, highest-lane-wins == max, and 0-fill is the max-scan identity —
// so one ds_permute replaces {init store + ds_max atomic + fence + read}.
__global__ __launch_bounds__(256) void ray_refine_kernel(
    const float* __restrict__ lengths,      // [n_rays, 64]
    const float* __restrict__ ray_weights,  // [n_rays, 64]
    float* __restrict__ out,                // [n_rays, 128]
    int n_rays)
{
    const int lane = threadIdx.x & 63;
    const int wid  = threadIdx.x >> 6;
    int ray = blockIdx.x * WPB + wid;
    if (ray >= n_rays) ray = n_rays - 1;

    const size_t base = (size_t)ray * 64;
    const float z  = lengths[base + lane];
    const float wf = ray_weights[base + lane];

    // cdf_k = (sum_{i<k} w_i)/total where w_i = ray_weights[i+1]+eps, i in [0,62).
    // Lane k's scan input = wf[k]+eps for k in [1,62]; 0 otherwise.
    // inclusive-scan(lane k) = total*cdf_k; scan(lane 62) = total.
    const float win = ((unsigned)(lane - 1) < 62u) ? (wf + EPS) : 0.0f;
    const float x = wave_scan_sum(win);
    const float total = readlane_f(x, 62);
    const float cv = x * __builtin_amdgcn_rcpf(total);  // cdf value at this lane

    // m_k = smallest j with cv_k*63 <= j == ceil(cv*63) (exact; tie flips at bin
    // boundaries perturb the continuous interpolant by O(ulp) only).
    // Clamp to 63: rounding-induced m=64 lands at slot 63, affecting only
    // ind_63, which is forced to its true value 63 by lane 63's own push
    // (min(lane+1,63) = 63) — so no drop-condition needed at all.
    int m = (int)ceilf(cv * 63.0f);
    m = min(m, 63);                          // m in [0,63], non-decreasing in lane
    const int scat = __builtin_amdgcn_ds_permute(m << 2, min(lane + 1, 63));

    // ind_j = #{k: m_k <= j} = max-scan of scattered (k+1)  (m_k non-decreasing)
    const int ind = wave_scan_max(scat);     // in [1,63]

    // Gather z[ind-1], z[ind], z[min(ind+1,63)], cv[ind-1], cv[ind] via bpermute.
    const int a1 = (ind - 1) << 2;
    const int a2 = ind << 2;
    const int a3 = min(ind + 1, 63) << 2;
    const float zb  = bperm_f(a1, z);        // z[below]
    const float zb1 = bperm_f(a2, z);        // z[below+1]
    const float z2  = bperm_f(a3, z);        // z[above+1] (garbage-safe if ind=63)
    const float cb  = bperm_f(a1, cv);       // cdf[below]
    const float ca  = bperm_f(a2, cv);       // cdf[above] (ind=63: ca-cb ~ ulp < EPS)

    const float bb = 0.5f * (zb + zb1);      // mids[below]
    const bool notlast = ind < 63;           // == (above > below) in the original
    const float ba = notlast ? 0.5f * (zb1 + z2) : bb;   // mids[above]
    const float denom = ca - cb;
    const float rden = (denom < EPS) ? 1.0f : __builtin_amdgcn_rcpf(denom);
    const float u = (lane >= 63) ? 1.0f : (float)lane * (1.0f / 63.0f);
    const float t = (u - cb) * rden;
    const float s = bb + t * (ba - bb);      // fine sample

    // rank of sample among z: structurally r in {ind, ind+1}, <= 63
    const int r = ind + ((notlast && zb1 <= s) ? 1 : 0);

    // rank of z among samples: cntB_i = #{j: r_j <= i} via permute-scatter +
    // max-scan (r non-decreasing). r >= 1 so slot 0 stays 0 -> cntB_0 = 0.
    const int scat2 = __builtin_amdgcn_ds_permute(r << 2, lane + 1);
    const int cntB = wave_scan_max(scat2);   // in [0,64]

    // merged positions (valid permutation: z-before-sample tie-break both ways)
    const size_t ob = (size_t)ray * 128;
    out[ob + lane + cntB] = z;   // pos = i + #{samples < z_i}
    out[ob + lane + r]    = s;   // pos = j + #{z <= sample_j}
}

extern "C" void kernel_launch(void* const* d_in, const int* in_sizes, int n_in,
                              void* d_out, int out_size, void* d_ws, size_t ws_size,
                              hipStream_t stream) {
    // inputs (setup_inputs order): origins, directions, lengths, xys, ray_weights
    const float* lengths     = (const float*)d_in[2];
    const float* ray_weights = (const float*)d_in[4];
    float* out = (float*)d_out;

    const int n_rays = in_sizes[2] / 64;
    const int grid = (n_rays + WPB - 1) / WPB;
    ray_refine_kernel<<<grid, 256, 0, stream>>>(lengths, ray_weights, out, n_rays);
}

// Round 3
// 430.740 us; speedup vs baseline: 1.0358x; 1.0358x over previous
//
#include <hip/hip_runtime.h>

#define EPS 1e-5f
#define WPB 4   // waves per 256-thread block
#define RPW 2   // rays per wave (independent ILP pipelines)

// DPP move with old=0: masked-out rows / OOB lanes return 0 (identity for sum
// and for max over non-negative values).
template<int CTRL, int RM>
__device__ __forceinline__ float dppf(float v) {
    return __int_as_float(__builtin_amdgcn_update_dpp(
        0, __float_as_int(v), CTRL, RM, 0xf, true));
}
template<int CTRL, int RM>
__device__ __forceinline__ int dppi(int v) {
    return __builtin_amdgcn_update_dpp(0, v, CTRL, RM, 0xf, true);
}

__device__ __forceinline__ float readlane_f(float v, int l) {
    return __int_as_float(__builtin_amdgcn_readlane(__float_as_int(v), l));
}
__device__ __forceinline__ float bperm_f(int byteaddr, float v) {
    return __int_as_float(__builtin_amdgcn_ds_bpermute(byteaddr, __float_as_int(v)));
}

// Inclusive 64-lane sum-scan: 4 row_shr steps + row_bcast15/31 cross-row finish.
__device__ __forceinline__ float wave_scan_sum(float x) {
    x += dppf<0x111, 0xf>(x);   // row_shr:1
    x += dppf<0x112, 0xf>(x);   // row_shr:2
    x += dppf<0x114, 0xf>(x);   // row_shr:4
    x += dppf<0x118, 0xf>(x);   // row_shr:8  -> inclusive within 16-lane row
    x += dppf<0x142, 0xa>(x);   // row_bcast15: rows 1 & 3 += prev-row total
    x += dppf<0x143, 0xc>(x);   // row_bcast31: rows 2 & 3 += lanes0-31 total
    return x;
}

// Inclusive 64-lane max-scan (values >= 0)
__device__ __forceinline__ int wave_scan_max(int x) {
    x = max(x, dppi<0x111, 0xf>(x));
    x = max(x, dppi<0x112, 0xf>(x));
    x = max(x, dppi<0x114, 0xf>(x));
    x = max(x, dppi<0x118, 0xf>(x));
    x = max(x, dppi<0x142, 0xa>(x));
    x = max(x, dppi<0x143, 0xc>(x));
    return x;
}

// One 64-lane wave handles RPW rays as independent register pipelines
// (lane i holds z[i], w[i] of each ray). Pure register-crossbar: no shared
// memory, no atomics, no barriers. The RPW chains interleave in the
// instruction stream, hiding each other's VMEM/DS latency.
__global__ __launch_bounds__(256) void ray_refine_kernel(
    const float* __restrict__ lengths,      // [n_rays, 64]
    const float* __restrict__ ray_weights,  // [n_rays, 64]
    float* __restrict__ out,                // [n_rays, 128]
    int n_rays)
{
    const int lane = threadIdx.x & 63;
    const int wid  = threadIdx.x >> 6;
    const int wave = blockIdx.x * WPB + wid;

    int   ray[RPW];
    float z[RPW], wf[RPW];
    #pragma unroll
    for (int q = 0; q < RPW; ++q) {
        int rr = wave * RPW + q;
        if (rr >= n_rays) rr = n_rays - 1;
        ray[q] = rr;
        const size_t base = (size_t)rr * 64;
        z[q]  = lengths[base + lane];       // both rays' loads issue up-front
        wf[q] = ray_weights[base + lane];
    }

    float s_out[RPW];
    int   r_out[RPW], cntB_out[RPW];

    #pragma unroll
    for (int q = 0; q < RPW; ++q) {
        // cdf_k = (sum_{i<k} w_i)/total, w_i = ray_weights[i+1]+eps, i in [0,62).
        // Lane k's scan input = wf[k]+eps for k in [1,62]; 0 otherwise.
        // inclusive-scan(lane k) = total*cdf_k; scan(lane 62) = total.
        const float win = ((unsigned)(lane - 1) < 62u) ? (wf[q] + EPS) : 0.0f;
        const float x = wave_scan_sum(win);
        const float total = readlane_f(x, 62);
        const float cv = x * __builtin_amdgcn_rcpf(total);

        // m_k = ceil(cv*63) clamped to 63 (rounding-induced m=64 lands at slot
        // 63; ind_63 is forced to its true value 63 by lane 63's own push).
        int m = (int)ceilf(cv * 63.0f);
        m = min(m, 63);
        // ds_permute scatter-max: highest lane wins on collisions, pushed value
        // (lane+1) is increasing in lane, 0-fill is the max-scan identity.
        const int scat = __builtin_amdgcn_ds_permute(m << 2, min(lane + 1, 63));
        const int ind = wave_scan_max(scat);     // ind_j = #{k: m_k <= j}, [1,63]

        // Gather z[ind-1], z[ind], z[min(ind+1,63)], cv[ind-1], cv[ind].
        // All 5 bpermutes depend only on ind -> issue in parallel.
        const int a1 = (ind - 1) << 2;
        const int a2 = ind << 2;
        const int a3 = min(ind + 1, 63) << 2;
        const float zb  = bperm_f(a1, z[q]);
        const float zb1 = bperm_f(a2, z[q]);
        const float z2  = bperm_f(a3, z[q]);
        const float cb  = bperm_f(a1, cv);
        const float ca  = bperm_f(a2, cv);   // ind=63: ca-cb ~ ulp < EPS

        const float bb = 0.5f * (zb + zb1);              // mids[below]
        const bool notlast = ind < 63;
        const float ba = notlast ? 0.5f * (zb1 + z2) : bb;  // mids[above]
        const float denom = ca - cb;
        const float rden = (denom < EPS) ? 1.0f : __builtin_amdgcn_rcpf(denom);
        const float u = (lane >= 63) ? 1.0f : (float)lane * (1.0f / 63.0f);
        const float t = (u - cb) * rden;
        const float s = bb + t * (ba - bb);              // fine sample

        // rank of sample among z: structurally r in {ind, ind+1}, <= 63
        const int r = ind + ((notlast && zb1 <= s) ? 1 : 0);

        // rank of z among samples: cntB_i = #{j: r_j <= i} (r non-decreasing;
        // r >= 1 so slot 0 stays 0 -> cntB_0 = 0)
        const int scat2 = __builtin_amdgcn_ds_permute(r << 2, lane + 1);
        const int cntB = wave_scan_max(scat2);

        s_out[q] = s;
        r_out[q] = r;
        cntB_out[q] = cntB;
    }

    #pragma unroll
    for (int q = 0; q < RPW; ++q) {
        // merged positions (valid permutation: z-before-sample tie-break)
        const size_t ob = (size_t)ray[q] * 128;
        out[ob + lane + cntB_out[q]] = z[q];      // pos = i + #{samples < z_i}
        out[ob + lane + r_out[q]]    = s_out[q];  // pos = j + #{z <= sample_j}
    }
}

extern "C" void kernel_launch(void* const* d_in, const int* in_sizes, int n_in,
                              void* d_out, int out_size, void* d_ws, size_t ws_size,
                              hipStream_t stream) {
    // inputs (setup_inputs order): origins, directions, lengths, xys, ray_weights
    const float* lengths     = (const float*)d_in[2];
    const float* ray_weights = (const float*)d_in[4];
    float* out = (float*)d_out;

    const int n_rays = in_sizes[2] / 64;
    const int rays_per_block = WPB * RPW;
    const int grid = (n_rays + rays_per_block - 1) / rays_per_block;
    ray_refine_kernel<<<grid, 256, 0, stream>>>(lengths, ray_weights, out, n_rays);
}